// Round 6
// baseline (260.843 us; speedup 1.0000x reference)
//
#include <hip/hip_runtime.h>
#include <stdint.h>

typedef unsigned long long u64;
typedef unsigned int uint;
typedef unsigned short u16;

#define NB   2048   // batch
#define NF   8      // frames
#define NT   8      // LIF timesteps
#define NS   128    // state dim
#define NH   512    // hidden
#define NAct 4      // action dim
#define HEAD_B 8    // batches per head block
#define TPB  256    // k_snn threads; thread owns h=tid and h=tid+256
#define LW   520    // spike list row width (padded to multiple of 8)

struct __align__(8) f2 { float x, y; };

// ---------------------------------------------------------------------------
// k_prep: pack weights as fp32 pairs (fp32->fp64 conversion at use is EXACT,
// so accumulating (double)w is bit-identical to fp64 tables at half the
// bytes). Wti1f[s][i] = (W_i1[i][s], W_i1[i+256][s]); Wt1f/Wt2f[k][i]
// likewise from W_h1/W_i2, plus zero row at k=NH (pad target; +0.0 is
// exact). Wtf1[j][h] fp32 for the head.
// ---------------------------------------------------------------------------
__global__ void k_prep(const float* __restrict__ W_i1,
                       const float* __restrict__ W_h1,
                       const float* __restrict__ W_i2,
                       const float* __restrict__ W_f1,
                       f2* __restrict__ Wti1f,
                       f2* __restrict__ Wt1f,
                       f2* __restrict__ Wt2f,
                       float* __restrict__ Wtf1)
{
    int idx = blockIdx.x * 256 + threadIdx.x;
    if (idx < NS * TPB) {                 // [s][i]
        int s = idx >> 8, i = idx & 255;
        f2 w; w.x = W_i1[i * NS + s]; w.y = W_i1[(i + 256) * NS + s];
        Wti1f[idx] = w;
    }
    if (idx < NH * TPB) {                 // [k][i]
        int k = idx >> 8, i = idx & 255;
        f2 w1; w1.x = W_h1[i * NH + k]; w1.y = W_h1[(i + 256) * NH + k];
        Wt1f[idx] = w1;
        f2 w2; w2.x = W_i2[i * NH + k]; w2.y = W_i2[(i + 256) * NH + k];
        Wt2f[idx] = w2;
    }
    if (idx < TPB) {                      // zero row k = NH
        f2 z; z.x = 0.f; z.y = 0.f;
        Wt1f[NH * TPB + idx] = z;
        Wt2f[NH * TPB + idx] = z;
    }
    if (idx < (NH + NAct) * NH) {         // [j][h]
        int j = idx / NH, hh = idx % NH;
        Wtf1[idx] = W_f1[hh * (NH + NAct) + j];
    }
}

// ---------------------------------------------------------------------------
// extraction: wave 0 turns spike masks into per-timestep k-index lists
// (ascending k), padded to a multiple of 8 with k=NH (zero weight row).
// ---------------------------------------------------------------------------
__device__ __forceinline__ void extract_lists(int tid,
                                              const u64 (*mask)[8],
                                              u16 (*s_idx)[LW],
                                              uint* s_cnt)
{
    if (tid < 64) {
        const int t = tid >> 3, w = tid & 7;
        u64 m = mask[t][w];
        int base = 0;
        for (int w2 = 0; w2 < w; ++w2) base += (int)__popcll(mask[t][w2]);
        uint kbase = (uint)(w << 6);
        while (m) {
            int kb = __builtin_ctzll(m);
            m &= m - 1;
            s_idx[t][base++] = (u16)(kbase + kb);
        }
        if (w == 7) {
            uint cnt = (uint)base;
            uint pad = (8u - (cnt & 7u)) & 7u;
            for (uint p = 0; p < pad; ++p) s_idx[t][cnt + p] = (u16)NH;
            s_cnt[t] = cnt + pad;
        }
    }
}

// ---------------------------------------------------------------------------
// gather8: sparse row-sum over a k-list, 8-event chunks, double-buffered
// software pipeline (issue chunk c+1 while consuming chunk c). Adds are
// strictly ascending-k fp64 -> bit-identical to the verified serial loop.
// ---------------------------------------------------------------------------
#define LOAD8(P0,P1,P2,P3,P4,P5,P6,P7, base)                               \
    {                                                                      \
        uint4 qv = *(const uint4*)(lst + (base));                          \
        uint o0 = __builtin_amdgcn_readfirstlane((qv.x & 0xFFFFu) << 11);  \
        uint o1 = __builtin_amdgcn_readfirstlane((qv.x >> 16) << 11);      \
        uint o2 = __builtin_amdgcn_readfirstlane((qv.y & 0xFFFFu) << 11);  \
        uint o3 = __builtin_amdgcn_readfirstlane((qv.y >> 16) << 11);      \
        uint o4 = __builtin_amdgcn_readfirstlane((qv.z & 0xFFFFu) << 11);  \
        uint o5 = __builtin_amdgcn_readfirstlane((qv.z >> 16) << 11);      \
        uint o6 = __builtin_amdgcn_readfirstlane((qv.w & 0xFFFFu) << 11);  \
        uint o7 = __builtin_amdgcn_readfirstlane((qv.w >> 16) << 11);      \
        P0 = *(const f2*)(tb + (o0 + hoff));                               \
        P1 = *(const f2*)(tb + (o1 + hoff));                               \
        P2 = *(const f2*)(tb + (o2 + hoff));                               \
        P3 = *(const f2*)(tb + (o3 + hoff));                               \
        P4 = *(const f2*)(tb + (o4 + hoff));                               \
        P5 = *(const f2*)(tb + (o5 + hoff));                               \
        P6 = *(const f2*)(tb + (o6 + hoff));                               \
        P7 = *(const f2*)(tb + (o7 + hoff));                               \
    }

#define ADD8(P0,P1,P2,P3,P4,P5,P6,P7)                                     \
    a0 += (double)P0.x; a1 += (double)P0.y;                               \
    a0 += (double)P1.x; a1 += (double)P1.y;                               \
    a0 += (double)P2.x; a1 += (double)P2.y;                               \
    a0 += (double)P3.x; a1 += (double)P3.y;                               \
    a0 += (double)P4.x; a1 += (double)P4.y;                               \
    a0 += (double)P5.x; a1 += (double)P5.y;                               \
    a0 += (double)P6.x; a1 += (double)P6.y;                               \
    a0 += (double)P7.x; a1 += (double)P7.y;

__device__ __forceinline__ void gather8(const char* tb, const u16* lst,
                                        uint n, uint hoff,
                                        double& a0, double& a1)
{
    if (!n) return;
    const uint m = n >> 3;                // chunks of 8 (n is a multiple of 8)
    f2 A0, A1, A2, A3, A4, A5, A6, A7;
    f2 B0, B1, B2, B3, B4, B5, B6, B7;
    LOAD8(A0, A1, A2, A3, A4, A5, A6, A7, 0)
    uint c = 1;
    for (; c + 1 < m; c += 2) {
        LOAD8(B0, B1, B2, B3, B4, B5, B6, B7, c << 3)
        ADD8(A0, A1, A2, A3, A4, A5, A6, A7)
        LOAD8(A0, A1, A2, A3, A4, A5, A6, A7, (c + 1) << 3)
        ADD8(B0, B1, B2, B3, B4, B5, B6, B7)
    }
    if (c < m) {
        LOAD8(B0, B1, B2, B3, B4, B5, B6, B7, c << 3)
        ADD8(A0, A1, A2, A3, A4, A5, A6, A7)
        ADD8(B0, B1, B2, B3, B4, B5, B6, B7)
    } else {
        ADD8(A0, A1, A2, A3, A4, A5, A6, A7)
    }
}

// ---------------------------------------------------------------------------
// k_snn: one block per batch. ih GEMV (fp64 from exact fp32 weights), 8
// frames of RNN1 (pipelined sparse gather + in-register LIF, double-buffered
// masks), RNN2 frame 7 (h2 == 0 provably: |x2| <= 22.7 << 999). Spike-path
// math fp64, op-for-op identical to the verified round-2..5 kernels.
// NOTE: no min-waves launch-bounds arg (round 4: forcing 8 waves/EU caps
// VGPR at 32 -> 345 MB/dispatch scratch spill, 4.3x slower).
// ---------------------------------------------------------------------------
__global__ __launch_bounds__(TPB) void k_snn(
    const float* __restrict__ state,   // [NB][NF][NS]
    const f2* __restrict__ Wti1f,      // [NS][TPB]
    const float* __restrict__ b_i1,
    const f2* __restrict__ Wt1f,       // [NH+1][TPB]
    const float* __restrict__ b_h1,
    const f2* __restrict__ Wt2f,       // [NH+1][TPB]
    const float* __restrict__ b_i2,
    const float* __restrict__ b_h2,
    float* __restrict__ vlast)         // [NB][NH] fp32
{
    const int b    = blockIdx.x;
    const int tid  = threadIdx.x;
    const int lane = tid & 63;
    const int wv   = tid >> 6;

    __shared__ double s_state[NF * NS];            // 8 KB, [f][s]
    __shared__ alignas(16) u16 s_idx[NT][LW];      // 8.1 KB
    __shared__ u64  s_mask[2][NT][8];              // 1 KB, double buffered
    __shared__ uint s_cnt[NT];

    // stage state (fp32 -> fp64, exact)
    {
        const float4* sp4 = (const float4*)(state + (size_t)b * NF * NS);
        float4 v4 = sp4[tid];
        s_state[tid * 4 + 0] = (double)v4.x;
        s_state[tid * 4 + 1] = (double)v4.y;
        s_state[tid * 4 + 2] = (double)v4.z;
        s_state[tid * 4 + 3] = (double)v4.w;
    }
    if (tid < 128) ((u64*)s_mask)[tid] = 0ull;     // frame 0 sees zero spikes
    __syncthreads();

    // ---- ih[f] for both owned columns, fp64, s-ascending fma ----
    double ih0[NF], ih1[NF];
#pragma unroll
    for (int f = 0; f < NF; ++f) { ih0[f] = 0.0; ih1[f] = 0.0; }
    for (int s = 0; s < NS; ++s) {
        f2 w = Wti1f[s * TPB + tid];
        double wx = (double)w.x, wy = (double)w.y;   // exact
#pragma unroll
        for (int f = 0; f < NF; ++f) {
            double sv = s_state[f * NS + s];
            ih0[f] = fma(sv, wx, ih0[f]);
            ih1[f] = fma(sv, wy, ih1[f]);
        }
    }
    {
        double bb0 = (double)b_i1[tid], bb1 = (double)b_i1[tid + 256];
#pragma unroll
        for (int f = 0; f < NF; ++f) { ih0[f] += bb0; ih1[f] += bb1; }
    }
    const double bh0  = (double)b_h1[tid];
    const double bh1v = (double)b_h1[tid + 256];
    const char*  w1b  = (const char*)Wt1f;
    const uint   hoff = (uint)tid * 8u;            // f2 row stride = TPB*8 = 2048 B

    // ---- 8 frames of RNN1 ----
    for (int f = 0; f < NF; ++f) {
        const int rb = f & 1, wb = rb ^ 1;
        __syncthreads();                           // prev masks final / lists consumed
        extract_lists(tid, s_mask[rb], s_idx, s_cnt);
        __syncthreads();

        const double ihc0 = ih0[0], ihc1 = ih1[0];
        double v0 = 0.0, v1 = 0.0;
        for (int t = 0; t < NT; ++t) {
            double a0 = 0.0, a1 = 0.0;
            gather8(w1b, s_idx[t], s_cnt[t], hoff, a0, a1);
            double x0 = (ihc0 + a0) + bh0;         // (ih + mm) + b, as reference
            v0 = v0 + (x0 - v0) * 0.5;             // v += (x - v)/TAU
            bool sp0 = (v0 - 1.0) >= 0.0;
            double x1 = (ihc1 + a1) + bh1v;
            v1 = v1 + (x1 - v1) * 0.5;
            bool sp1 = (v1 - 1.0) >= 0.0;
            u64 m0 = __ballot(sp0);
            u64 m1 = __ballot(sp1);
            if (lane == 0) { s_mask[wb][t][wv] = m0; s_mask[wb][t][wv + 4] = m1; }
            if (sp0) v0 = 0.0;                     // hard reset
            if (sp1) v1 = 0.0;
        }
#pragma unroll
        for (int j = 0; j < NF - 1; ++j) { ih0[j] = ih0[j + 1]; ih1[j] = ih1[j + 1]; }
    }

    // ---- RNN2, frame 7 only; frame 7 wrote its spikes into buffer 0 ----
    __syncthreads();
    extract_lists(tid, s_mask[0], s_idx, s_cnt);
    __syncthreads();

    {
        const char* w2b = (const char*)Wt2f;
        const double bi0 = (double)b_i2[tid], bi1 = (double)b_i2[tid + 256];
        const double bg0 = (double)b_h2[tid], bg1 = (double)b_h2[tid + 256];
        double v0 = 0.0, v1 = 0.0;
        for (int t = 0; t < NT; ++t) {
            double a0 = 0.0, a1 = 0.0;
            gather8(w2b, s_idx[t], s_cnt[t], hoff, a0, a1);
            double x0 = (a0 + bi0) + bg0;          // ((mm + b_i2) + 0) + b_h2
            v0 = v0 + (x0 - v0) * 0.5;
            if ((v0 - 999.0) >= 0.0) v0 = 0.0;     // faithful; never fires here
            double x1 = (a1 + bi1) + bg1;
            v1 = v1 + (x1 - v1) * 0.5;
            if ((v1 - 999.0) >= 0.0) v1 = 0.0;
        }
        vlast[(size_t)b * NH + tid]       = (float)v0;
        vlast[(size_t)b * NH + tid + 256] = (float)v1;
    }
}

// ---------------------------------------------------------------------------
// k_head: q = relu([v_last, action] @ W_f1.T + b_f1) @ W_f2.T + b_f2   (fp32)
// ---------------------------------------------------------------------------
__global__ __launch_bounds__(512) void k_head(
    const float* __restrict__ vlast,
    const float* __restrict__ action,
    const float* __restrict__ Wtf1,    // [516][512]
    const float* __restrict__ b_f1,
    const float* __restrict__ W_f2,
    const float* __restrict__ b_f2,
    float* __restrict__ q)
{
    const int h    = threadIdx.x;
    const int lane = h & 63;
    const int wv   = h >> 6;
    const int b0   = blockIdx.x * HEAD_B;

    __shared__ float s_x[HEAD_B][NH + NAct];
    for (int i = h; i < HEAD_B * NH; i += 512) {
        int bi = i / NH, j = i % NH;
        s_x[bi][j] = vlast[(size_t)(b0 + bi) * NH + j];
    }
    if (h < HEAD_B * NAct) {
        int bi = h / NAct, j = h % NAct;
        s_x[bi][NH + j] = action[(b0 + bi) * NAct + j];
    }
    __syncthreads();

    float acc[HEAD_B] = {0, 0, 0, 0, 0, 0, 0, 0};
#pragma unroll 4
    for (int j = 0; j < NH + NAct; ++j) {
        float w = Wtf1[j * NH + h];
#pragma unroll
        for (int i = 0; i < HEAD_B; ++i)
            acc[i] = fmaf(s_x[i][j], w, acc[i]);
    }

    const float bf = b_f1[h];
    const float w2 = W_f2[h];
    float p[HEAD_B];
#pragma unroll
    for (int i = 0; i < HEAD_B; ++i) {
        float hv = acc[i] + bf;
        hv = hv < 0.f ? 0.f : hv;
        p[i] = hv * w2;
    }
#pragma unroll
    for (int off = 32; off; off >>= 1) {
#pragma unroll
        for (int i = 0; i < HEAD_B; ++i)
            p[i] += __shfl_down(p[i], off);
    }
    __shared__ float red[8][HEAD_B];
    if (lane == 0) {
#pragma unroll
        for (int i = 0; i < HEAD_B; ++i) red[wv][i] = p[i];
    }
    __syncthreads();
    if (h < HEAD_B) {
        float s = 0.f;
#pragma unroll
        for (int w = 0; w < 8; ++w) s += red[w][h];
        q[b0 + h] = s + b_f2[0];
    }
}

// ---------------------------------------------------------------------------
extern "C" void kernel_launch(void* const* d_in, const int* in_sizes, int n_in,
                              void* d_out, int out_size, void* d_ws, size_t ws_size,
                              hipStream_t stream)
{
    const float* state  = (const float*)d_in[0];
    const float* action = (const float*)d_in[1];
    const float* W_i1   = (const float*)d_in[2];
    const float* b_i1   = (const float*)d_in[3];
    const float* W_h1   = (const float*)d_in[4];
    const float* b_h1   = (const float*)d_in[5];
    const float* W_i2   = (const float*)d_in[6];
    const float* b_i2   = (const float*)d_in[7];
    // d_in[8] = W_h2: provably unused (h2 spikes are identically zero)
    const float* b_h2   = (const float*)d_in[9];
    const float* W_f1   = (const float*)d_in[10];
    const float* b_f1   = (const float*)d_in[11];
    const float* W_f2   = (const float*)d_in[12];
    const float* b_f2   = (const float*)d_in[13];

    char* ws = (char*)d_ws;
    f2*    Wti1f = (f2*)(ws);                       // 128*256*8 = 256 KB
    f2*    Wt1f  = (f2*)(ws + 262144);              // 513*256*8 = 1.002 MB
    f2*    Wt2f  = (f2*)(ws + 1312768);             // 513*256*8 = 1.002 MB
    float* Wtf1  = (float*)(ws + 2363392);          // 516*512*4 = 1.008 MB
    float* vlast = (float*)(ws + 3420160);          // 2048*512*4 = 4 MB

    k_prep<<<((NH + NAct) * NH + 255) / 256, 256, 0, stream>>>(
        W_i1, W_h1, W_i2, W_f1, Wti1f, Wt1f, Wt2f, Wtf1);

    k_snn<<<NB, TPB, 0, stream>>>(state, Wti1f, b_i1, Wt1f, b_h1,
                                  Wt2f, b_i2, b_h2, vlast);

    k_head<<<NB / HEAD_B, 512, 0, stream>>>(vlast, action, Wtf1, b_f1,
                                            W_f2, b_f2, (float*)d_out);
}

// Round 7
// 227.232 us; speedup vs baseline: 1.1479x; 1.1479x over previous
//
#include <hip/hip_runtime.h>
#include <stdint.h>

typedef unsigned long long u64;
typedef unsigned int uint;
typedef unsigned short u16;

#define NB   2048   // batch
#define NF   8      // frames
#define NT   8      // LIF timesteps
#define NS   128    // state dim
#define NH   512    // hidden
#define NAct 4      // action dim
#define HEAD_B 8    // batches per head block
#define TPB  512    // k_snn threads; thread owns column h = tid (1 col/thread)
#define LW   516    // spike list row width (padded to multiple of 4)

// ---------------------------------------------------------------------------
// k_prep: plain f32 transposes. Wti1s[s][h] = W_i1[h][s]; Wt1s/Wt2s[k][h]
// from W_h1/W_i2 with zero row at k=NH (pad target; +0.0 is exact);
// Wtf1[j][h] for the head. fp32->fp64 cvt at use is EXACT, so fp64
// accumulation from these tables is bit-identical to fp64 tables.
// ---------------------------------------------------------------------------
__global__ void k_prep(const float* __restrict__ W_i1,
                       const float* __restrict__ W_h1,
                       const float* __restrict__ W_i2,
                       const float* __restrict__ W_f1,
                       float* __restrict__ Wti1s,
                       float* __restrict__ Wt1s,
                       float* __restrict__ Wt2s,
                       float* __restrict__ Wtf1)
{
    int idx = blockIdx.x * 256 + threadIdx.x;
    if (idx < NS * NH) {                  // [s][h]
        int s = idx >> 9, h = idx & 511;
        Wti1s[idx] = W_i1[h * NS + s];
    }
    if (idx < NH * NH) {                  // [k][h]
        int k = idx >> 9, h = idx & 511;
        Wt1s[idx] = W_h1[h * NH + k];
        Wt2s[idx] = W_i2[h * NH + k];
    }
    if (idx < NH) {                       // zero row k = NH
        Wt1s[NH * NH + idx] = 0.f;
        Wt2s[NH * NH + idx] = 0.f;
    }
    if (idx < (NH + NAct) * NH) {         // [j][h]
        int j = idx / NH, hh = idx % NH;
        Wtf1[idx] = W_f1[hh * (NH + NAct) + j];
    }
}

// ---------------------------------------------------------------------------
// extraction, wave-parallel: wave t's lanes 0..7 turn timestep t's spike
// masks into a k-index list (ascending k), padded to x4 with k=NH.
// ---------------------------------------------------------------------------
__device__ __forceinline__ void extract_lists(int lane, int t,
                                              const u64 (*mask)[8],
                                              u16 (*s_idx)[LW],
                                              uint* s_cnt)
{
    if (lane < 8) {
        const int w = lane;
        u64 m = mask[t][w];
        int base = 0;
        for (int w2 = 0; w2 < w; ++w2) base += (int)__popcll(mask[t][w2]);
        uint kbase = (uint)(w << 6);
        while (m) {
            int kb = __builtin_ctzll(m);
            m &= m - 1;
            s_idx[t][base++] = (u16)(kbase + kb);
        }
        if (w == 7) {
            uint cnt = (uint)base;
            uint pad = (4u - (cnt & 3u)) & 3u;
            for (uint p = 0; p < pad; ++p) s_idx[t][cnt + p] = (u16)NH;
            s_cnt[t] = cnt + pad;
        }
    }
}

// ---------------------------------------------------------------------------
// gather4: sparse row-sum over a k-list, 4-event chunks, double-buffered
// (issue chunk c+1 while consuming chunk c). Adds are strictly ascending-k
// fp64 of exactly-cvt'd fp32 -> bit-identical to the verified kernels.
// Row offset is wave-uniform (readfirstlane -> SGPR), payload load is
// saddr + tid*4 -> fully coalesced 256 B per wave.
// ---------------------------------------------------------------------------
#define LOAD4(P0,P1,P2,P3, base)                                           \
    {                                                                      \
        uint2 qv = *(const uint2*)(lst + (base));                          \
        uint o0 = __builtin_amdgcn_readfirstlane((qv.x & 0xFFFFu) << 11);  \
        uint o1 = __builtin_amdgcn_readfirstlane((qv.x >> 16) << 11);      \
        uint o2 = __builtin_amdgcn_readfirstlane((qv.y & 0xFFFFu) << 11);  \
        uint o3 = __builtin_amdgcn_readfirstlane((qv.y >> 16) << 11);      \
        P0 = *(const float*)(tb + (o0 + hoff));                            \
        P1 = *(const float*)(tb + (o1 + hoff));                            \
        P2 = *(const float*)(tb + (o2 + hoff));                            \
        P3 = *(const float*)(tb + (o3 + hoff));                            \
    }

#define ADD4(P0,P1,P2,P3)                                                 \
    a += (double)P0; a += (double)P1; a += (double)P2; a += (double)P3;

__device__ __forceinline__ double gather4(const char* tb, const u16* lst,
                                          uint n, uint hoff)
{
    double a = 0.0;
    if (!n) return a;
    const uint m = n >> 2;                // chunks of 4 (n is a multiple of 4)
    float A0, A1, A2, A3, B0, B1, B2, B3;
    LOAD4(A0, A1, A2, A3, 0)
    uint c = 1;
    for (; c + 1 < m; c += 2) {
        LOAD4(B0, B1, B2, B3, c << 2)
        ADD4(A0, A1, A2, A3)
        LOAD4(A0, A1, A2, A3, (c + 1) << 2)
        ADD4(B0, B1, B2, B3)
    }
    if (c < m) {
        LOAD4(B0, B1, B2, B3, c << 2)
        ADD4(A0, A1, A2, A3)
        ADD4(B0, B1, B2, B3)
    } else {
        ADD4(A0, A1, A2, A3)
    }
    return a;
}

// ---------------------------------------------------------------------------
// k_snn: one block per batch, 8 waves, 1 column per thread. ih GEMV (fp64
// from exact fp32 weights), 8 frames of RNN1 (pipelined sparse gather +
// in-register LIF, double-buffered masks), RNN2 frame 7 (h2 == 0 provably:
// |x2| <= 22.7 << 999). Spike-path math fp64, op-for-op identical to the
// verified round-2..6 kernels.
// NOTE: no min-waves launch-bounds arg (round 4: forcing 8 waves/EU caps
// VGPR at 32 -> 345 MB/dispatch scratch spill, 4.3x slower).
// ---------------------------------------------------------------------------
__global__ __launch_bounds__(TPB) void k_snn(
    const float* __restrict__ state,   // [NB][NF][NS]
    const float* __restrict__ Wti1s,   // [NS][NH]
    const float* __restrict__ b_i1,
    const float* __restrict__ Wt1s,    // [NH+1][NH]
    const float* __restrict__ b_h1,
    const float* __restrict__ Wt2s,    // [NH+1][NH]
    const float* __restrict__ b_i2,
    const float* __restrict__ b_h2,
    float* __restrict__ vlast)         // [NB][NH] fp32
{
    const int b    = blockIdx.x;
    const int tid  = threadIdx.x;
    const int lane = tid & 63;
    const int wv   = tid >> 6;

    __shared__ double s_state[NF * NS];            // 8 KB, [f][s]
    __shared__ alignas(16) u16 s_idx[NT][LW];      // 8.06 KB
    __shared__ u64  s_mask[2][NT][8];              // 1 KB, double buffered
    __shared__ uint s_cnt[NT];

    // stage state (fp32 -> fp64, exact); 512 threads x float2 covers 1024
    {
        const float2* sp2 = (const float2*)(state + (size_t)b * NF * NS);
        float2 v2 = sp2[tid];
        s_state[tid * 2 + 0] = (double)v2.x;
        s_state[tid * 2 + 1] = (double)v2.y;
    }
    if (tid < 128) ((u64*)s_mask)[tid] = 0ull;     // frame 0 sees zero spikes
    __syncthreads();

    // ---- ih[f] for this thread's column, fp64, s-ascending fma ----
    double ih0[NF];
#pragma unroll
    for (int f = 0; f < NF; ++f) ih0[f] = 0.0;
    for (int s = 0; s < NS; ++s) {
        double w = (double)Wti1s[s * NH + tid];    // exact cvt
#pragma unroll
        for (int f = 0; f < NF; ++f)
            ih0[f] = fma(s_state[f * NS + s], w, ih0[f]);
    }
    {
        double bb = (double)b_i1[tid];
#pragma unroll
        for (int f = 0; f < NF; ++f) ih0[f] += bb;
    }
    const double bh1v = (double)b_h1[tid];
    const char*  w1b  = (const char*)Wt1s;
    const uint   hoff = (uint)tid * 4u;            // f32 row stride = 2048 B

    // ---- 8 frames of RNN1 ----
    for (int f = 0; f < NF; ++f) {
        const int rb = f & 1, wb = rb ^ 1;
        __syncthreads();                           // prev masks final / lists consumed
        extract_lists(lane, wv, s_mask[rb], s_idx, s_cnt);
        __syncthreads();

        const double ihc = ih0[0];
        double v = 0.0;
        for (int t = 0; t < NT; ++t) {
            double a = gather4(w1b, s_idx[t], s_cnt[t], hoff);
            double x = (ihc + a) + bh1v;           // (ih + mm) + b, as reference
            v = v + (x - v) * 0.5;                 // v += (x - v)/TAU
            bool sp = (v - 1.0) >= 0.0;
            u64 m = __ballot(sp);
            if (lane == 0) s_mask[wb][t][wv] = m;
            if (sp) v = 0.0;                       // hard reset
        }
#pragma unroll
        for (int j = 0; j < NF - 1; ++j) ih0[j] = ih0[j + 1];
    }

    // ---- RNN2, frame 7 only; frame 7 wrote its spikes into buffer 0 ----
    __syncthreads();
    extract_lists(lane, wv, s_mask[0], s_idx, s_cnt);
    __syncthreads();

    {
        const char* w2b = (const char*)Wt2s;
        const double bi = (double)b_i2[tid];
        const double bg = (double)b_h2[tid];
        double v = 0.0;
        for (int t = 0; t < NT; ++t) {
            double a = gather4(w2b, s_idx[t], s_cnt[t], hoff);
            double x = (a + bi) + bg;              // ((mm + b_i2) + 0) + b_h2
            v = v + (x - v) * 0.5;
            if ((v - 999.0) >= 0.0) v = 0.0;       // faithful; never fires here
        }
        vlast[(size_t)b * NH + tid] = (float)v;
    }
}

// ---------------------------------------------------------------------------
// k_head: q = relu([v_last, action] @ W_f1.T + b_f1) @ W_f2.T + b_f2   (fp32)
// ---------------------------------------------------------------------------
__global__ __launch_bounds__(512) void k_head(
    const float* __restrict__ vlast,
    const float* __restrict__ action,
    const float* __restrict__ Wtf1,    // [516][512]
    const float* __restrict__ b_f1,
    const float* __restrict__ W_f2,
    const float* __restrict__ b_f2,
    float* __restrict__ q)
{
    const int h    = threadIdx.x;
    const int lane = h & 63;
    const int wv   = h >> 6;
    const int b0   = blockIdx.x * HEAD_B;

    __shared__ float s_x[HEAD_B][NH + NAct];
    for (int i = h; i < HEAD_B * NH; i += 512) {
        int bi = i / NH, j = i % NH;
        s_x[bi][j] = vlast[(size_t)(b0 + bi) * NH + j];
    }
    if (h < HEAD_B * NAct) {
        int bi = h / NAct, j = h % NAct;
        s_x[bi][NH + j] = action[(b0 + bi) * NAct + j];
    }
    __syncthreads();

    float acc[HEAD_B] = {0, 0, 0, 0, 0, 0, 0, 0};
#pragma unroll 4
    for (int j = 0; j < NH + NAct; ++j) {
        float w = Wtf1[j * NH + h];
#pragma unroll
        for (int i = 0; i < HEAD_B; ++i)
            acc[i] = fmaf(s_x[i][j], w, acc[i]);
    }

    const float bf = b_f1[h];
    const float w2 = W_f2[h];
    float p[HEAD_B];
#pragma unroll
    for (int i = 0; i < HEAD_B; ++i) {
        float hv = acc[i] + bf;
        hv = hv < 0.f ? 0.f : hv;
        p[i] = hv * w2;
    }
#pragma unroll
    for (int off = 32; off; off >>= 1) {
#pragma unroll
        for (int i = 0; i < HEAD_B; ++i)
            p[i] += __shfl_down(p[i], off);
    }
    __shared__ float red[8][HEAD_B];
    if (lane == 0) {
#pragma unroll
        for (int i = 0; i < HEAD_B; ++i) red[wv][i] = p[i];
    }
    __syncthreads();
    if (h < HEAD_B) {
        float s = 0.f;
#pragma unroll
        for (int w = 0; w < 8; ++w) s += red[w][h];
        q[b0 + h] = s + b_f2[0];
    }
}

// ---------------------------------------------------------------------------
extern "C" void kernel_launch(void* const* d_in, const int* in_sizes, int n_in,
                              void* d_out, int out_size, void* d_ws, size_t ws_size,
                              hipStream_t stream)
{
    const float* state  = (const float*)d_in[0];
    const float* action = (const float*)d_in[1];
    const float* W_i1   = (const float*)d_in[2];
    const float* b_i1   = (const float*)d_in[3];
    const float* W_h1   = (const float*)d_in[4];
    const float* b_h1   = (const float*)d_in[5];
    const float* W_i2   = (const float*)d_in[6];
    const float* b_i2   = (const float*)d_in[7];
    // d_in[8] = W_h2: provably unused (h2 spikes are identically zero)
    const float* b_h2   = (const float*)d_in[9];
    const float* W_f1   = (const float*)d_in[10];
    const float* b_f1   = (const float*)d_in[11];
    const float* W_f2   = (const float*)d_in[12];
    const float* b_f2   = (const float*)d_in[13];

    char* ws = (char*)d_ws;
    float* Wti1s = (float*)(ws);                    // 128*512*4 = 256 KB
    float* Wt1s  = (float*)(ws + 262144);           // 513*512*4 = 1.050 MB
    float* Wt2s  = (float*)(ws + 1312768);          // 513*512*4 = 1.050 MB
    float* Wtf1  = (float*)(ws + 2363392);          // 516*512*4 = 1.057 MB
    float* vlast = (float*)(ws + 3420160);          // 2048*512*4 = 4 MB

    k_prep<<<((NH + NAct) * NH + 255) / 256, 256, 0, stream>>>(
        W_i1, W_h1, W_i2, W_f1, Wti1s, Wt1s, Wt2s, Wtf1);

    k_snn<<<NB, TPB, 0, stream>>>(state, Wti1s, b_i1, Wt1s, b_h1,
                                  Wt2s, b_i2, b_h2, vlast);

    k_head<<<NB / HEAD_B, 512, 0, stream>>>(vlast, action, Wtf1, b_f1,
                                            W_f2, b_f2, (float*)d_out);
}